// Round 6
// baseline (731.723 us; speedup 1.0000x reference)
//
#include <hip/hip_runtime.h>
#include <hip/hip_cooperative_groups.h>
#include <hip/hip_bf16.h>

namespace cg = cooperative_groups;

typedef unsigned int uint;
typedef float v2f __attribute__((ext_vector_type(2)));

#define NATOMS 20000
#define NEDGES 640000
#define FD 128
#define F3 384
#define NR 20
#define MAPB 16                     // atoms per MLP task
#define GA 10                       // atoms per gather chunk
#define NCHUNK (NATOMS / GA)        // 2000
#define CAPMAX 80                   // bin capacity (mean degree 32, ~11 sigma)
#define BLK 128
#define GRID_TARGET 2048
#define MLP_TASKS (NATOMS / MAPB)   // 1250
#define XMPSTRIDE (FD * 3 * 4)      // 1536 B per atom in xmp

__device__ __forceinline__ uint f2bfu(float f) {   // f32 -> bf16 bits, RNE
  const uint u = __float_as_uint(f);
  return (u + 0x7FFFu + ((u >> 16) & 1u)) >> 16;
}
__device__ __forceinline__ float bflo(uint u) { return __uint_as_float(u << 16); }
__device__ __forceinline__ float bfhi(uint u) { return __uint_as_float(u & 0xFFFF0000u); }

// ---------------------------------------------------------------------------
// ONE cooperative kernel:
//  phase A1: prep  -- grid-stride edges; 16B record {ew0,ew1,ew2, j*1536}
//            into atom i's fixed bin (atomicAdd slot). No CSR build.
//  phase A2: mlp   -- grid-stride 16-atom tasks; silu MLP, bf16-pack 12B
//            records into xmp. Independent of A1 -> blocks interleave both.
//  grid.sync (device fence for cross-XCD L2 visibility)
//  phase B:  gather -- grid-stride 10-atom chunks; inner loop identical to
//            the verified R5 kernel (194us standalone).
// Replaces 4 dispatches (memset stays) -> no inter-kernel drains, prep/mlp
// overlap. 16KB smem aliased per phase; launch_bounds(128,4) caps VGPR at
// 128 (mlp ~95, gather ~110 both fit; gather path was fine even at cap 170).
// ---------------------------------------------------------------------------
__global__ __launch_bounds__(BLK, 4) void fused_kernel(
    const int* __restrict__ eidx, const float* __restrict__ ew,
    int* __restrict__ cnt, uint4* __restrict__ basisS, int cap,
    const float* __restrict__ q, const float* __restrict__ mu,
    const float* __restrict__ W1, const float* __restrict__ b1,
    const float* __restrict__ W2, const float* __restrict__ b2v,
    uint* __restrict__ xmp,
    const float* __restrict__ Wf, const float* __restrict__ bfv,
    float* __restrict__ out)
{
  __shared__ float smem[2 * MAPB * FD];   // 16 KB, aliased per phase
  const int t = threadIdx.x;
  const int gsz = gridDim.x;

  // ------------------------- phase A1: prep -------------------------------
  for (int e = blockIdx.x * BLK + t; e < NEDGES; e += gsz * BLK) {
    const int i = eidx[e];
    const int j = eidx[NEDGES + e];
    const int pos = atomicAdd(&cnt[i], 1);
    if (pos < cap) {                           // guard (never trips at cap=80)
      uint4 r;
      r.x = __float_as_uint(ew[(size_t)e * 3 + 0]);
      r.y = __float_as_uint(ew[(size_t)e * 3 + 1]);
      r.z = __float_as_uint(ew[(size_t)e * 3 + 2]);
      r.w = (uint)j * (uint)XMPSTRIDE;         // byte offset into xmp
      basisS[(size_t)i * cap + pos] = r;
    }
  }

  // ------------------------- phase A2: mlp --------------------------------
  {
    float* qL = smem;                 // [MAPB][FD]
    float* hL = smem + MAPB * FD;     // [MAPB][FD]
    for (int task = blockIdx.x; task < MLP_TASKS; task += gsz) {
      const int a0 = task * MAPB;
      __syncthreads();                // protect smem reuse
      #pragma unroll
      for (int a = 0; a < MAPB; ++a) qL[a * FD + t] = q[(size_t)(a0 + a) * FD + t];
      __syncthreads();

      float hacc[MAPB];
      const float bb1 = b1[t];
      #pragma unroll
      for (int a = 0; a < MAPB; ++a) hacc[a] = bb1;
      for (int i = 0; i < FD; i += 4) {
        const float w0 = W1[(size_t)i * FD + t];
        const float w1 = W1[(size_t)(i + 1) * FD + t];
        const float w2 = W1[(size_t)(i + 2) * FD + t];
        const float w3 = W1[(size_t)(i + 3) * FD + t];
        #pragma unroll
        for (int a = 0; a < MAPB; ++a) {
          const float4 qv = *(const float4*)&qL[a * FD + i];   // b128 broadcast
          hacc[a] += qv.x * w0 + qv.y * w1 + qv.z * w2 + qv.w * w3;
        }
      }
      #pragma unroll
      for (int a = 0; a < MAPB; ++a) hL[a * FD + t] = hacc[a] / (1.f + __expf(-hacc[a]));
      __syncthreads();

      float x0[MAPB], x1[MAPB], x2[MAPB];
      const float c0 = b2v[t], c1 = b2v[FD + t], c2 = b2v[2 * FD + t];
      #pragma unroll
      for (int a = 0; a < MAPB; ++a) { x0[a] = c0; x1[a] = c1; x2[a] = c2; }
      for (int i = 0; i < FD; i += 4) {
        const float wa0 = W2[(size_t)i * F3 + t];
        const float wa1 = W2[(size_t)(i + 1) * F3 + t];
        const float wa2 = W2[(size_t)(i + 2) * F3 + t];
        const float wa3 = W2[(size_t)(i + 3) * F3 + t];
        const float wb0 = W2[(size_t)i * F3 + FD + t];
        const float wb1 = W2[(size_t)(i + 1) * F3 + FD + t];
        const float wb2 = W2[(size_t)(i + 2) * F3 + FD + t];
        const float wb3 = W2[(size_t)(i + 3) * F3 + FD + t];
        const float wc0 = W2[(size_t)i * F3 + 2 * FD + t];
        const float wc1 = W2[(size_t)(i + 1) * F3 + 2 * FD + t];
        const float wc2 = W2[(size_t)(i + 2) * F3 + 2 * FD + t];
        const float wc3 = W2[(size_t)(i + 3) * F3 + 2 * FD + t];
        #pragma unroll
        for (int a = 0; a < MAPB; ++a) {
          const float4 hv = *(const float4*)&hL[a * FD + i];   // b128 broadcast
          x0[a] += hv.x * wa0 + hv.y * wa1 + hv.z * wa2 + hv.w * wa3;
          x1[a] += hv.x * wb0 + hv.y * wb1 + hv.z * wb2 + hv.w * wb3;
          x2[a] += hv.x * wc0 + hv.y * wc1 + hv.z * wc2 + hv.w * wc3;
        }
      }
      #pragma unroll
      for (int a = 0; a < MAPB; ++a) {
        const int n = a0 + a;
        const float* ma = mu + (size_t)n * F3;
        const float m0 = ma[t], m1 = ma[FD + t], m2 = ma[2 * FD + t];
        uint* dst = xmp + ((size_t)n * FD + t) * 3;
        dst[0] = f2bfu(x0[a]) | (f2bfu(x1[a]) << 16);
        dst[1] = f2bfu(x2[a]) | (f2bfu(m0) << 16);
        dst[2] = f2bfu(m1)    | (f2bfu(m2) << 16);
      }
    }
  }

  // device-scope visibility (cross-XCD L2) then grid barrier
  __threadfence();
  cg::this_grid().sync();

  // ------------------------- phase B: gather ------------------------------
  {
    float (*fb)[28] = reinterpret_cast<float (*)[28]>(smem);  // 7 KB of smem
    const int tb = t * 12;
    const char* xmpC = (const char*)xmp;
    const size_t NQ = (size_t)NATOMS * FD;

    v2f wf0[10], wf1[10], wf2[10];
    #pragma unroll
    for (int r = 0; r < 10; ++r) {
      wf0[r] = (v2f){Wf[(size_t)(2 * r) * F3 + t],       Wf[(size_t)(2 * r + 1) * F3 + t]};
      wf1[r] = (v2f){Wf[(size_t)(2 * r) * F3 + 128 + t], Wf[(size_t)(2 * r + 1) * F3 + 128 + t]};
      wf2[r] = (v2f){Wf[(size_t)(2 * r) * F3 + 256 + t], Wf[(size_t)(2 * r + 1) * F3 + 256 + t]};
    }
    const float bias0 = bfv[t], bias1 = bfv[128 + t], bias2 = bfv[256 + t];

    for (int c = blockIdx.x; c < NCHUNK; c += gsz) {
      const int aEnd = (c + 1) * GA;
      for (int a = c * GA; a < aEnd; ++a) {
        float acq = 0.f, ac0 = 0.f, ac1 = 0.f, ac2 = 0.f;

        auto edge_compute = [&](int k, uint pX, uint pY, uint pZ) {
          const float* fk = fb[k];
          const float4 M = *(const float4*)(fk + 20);  // env, dir0..2
          v2f s0 = (v2f){0.f, 0.f}, s1 = (v2f){0.f, 0.f}, s2 = (v2f){0.f, 0.f};
          #pragma unroll
          for (int r4 = 0; r4 < 5; ++r4) {             // 5x ds_read_b128 bcast
            const float4 bv = ((const float4*)fk)[r4];
            const v2f blo = (v2f){bv.x, bv.y};
            const v2f bhi = (v2f){bv.z, bv.w};
            s0 += blo * wf0[2 * r4]; s0 += bhi * wf0[2 * r4 + 1];
            s1 += blo * wf1[2 * r4]; s1 += bhi * wf1[2 * r4 + 1];
            s2 += blo * wf2[2 * r4]; s2 += bhi * wf2[2 * r4 + 1];
          }
          const float env = M.x;
          const float f0 = s0.x + s0.y + env * bias0;
          const float f1 = s1.x + s1.y + env * bias1;
          const float f2 = s2.x + s2.y + env * bias2;

          acq += f0 * bflo(pX);
          const float dmuR = f1 * bfhi(pX);
          const float dmm  = f2 * bflo(pY);
          ac0 += dmuR * M.y + dmm * bfhi(pY);
          ac1 += dmuR * M.z + dmm * bflo(pZ);
          ac2 += dmuR * M.w + dmm * bfhi(pZ);
        };

        int deg = cnt[a];
        if (deg > cap) deg = cap;
        const uint4* bin = basisS + (size_t)a * cap;

        for (int cb = 0; cb < deg; cb += 64) {
          const int nn = min(64, deg - cb);
          __syncthreads();                       // fb reuse hazard
          if (t < nn) {
            const uint4 r = bin[cb + t];         // direct 16B coalesced load
            const float w0 = __uint_as_float(r.x);
            const float w1 = __uint_as_float(r.y);
            const float w2 = __uint_as_float(r.z);
            const float d = sqrtf(w0 * w0 + w1 * w1 + w2 * w2);
            const float invd = 1.f / d;
            float s1v, c1v;
            __sincosf(d * 0.628318530717958f, &s1v, &c1v);  // theta = pi*d/5
            const float env = (d < 5.f) ? 0.5f * (c1v + 1.f) : 0.f;
            fb[t][20] = env;
            fb[t][21] = w0 * invd;
            fb[t][22] = w1 * invd;
            fb[t][23] = w2 * invd;
            fb[t][24] = __uint_as_float(r.w);               // jbyte bits
            float vp = 0.f, vc = s1v * env * invd;
            const float tc2 = 2.f * c1v;
            #pragma unroll
            for (int r2 = 0; r2 < NR; ++r2) { fb[t][r2] = vc; const float vn = tc2 * vc - vp; vp = vc; vc = vn; }
          }
          __syncthreads();

          // prologue: fill both register sets (edges 0 and 1, clamped)
          uint aX, aY, aZ, bX, bY, bZ;
          {
            const uint j0 = __float_as_uint(fb[0][24]);
            const uint* xp = (const uint*)(xmpC + j0 + tb);
            aX = xp[0]; aY = xp[1]; aZ = xp[2];
            const int k1 = (nn > 1) ? 1 : 0;
            const uint j1 = __float_as_uint(fb[k1][24]);
            const uint* yp = (const uint*)(xmpC + j1 + tb);
            bX = yp[0]; bY = yp[1]; bZ = yp[2];
          }

          int k = 0;
          while (k < nn) {
            {                                    // edge k (set A)
              const uint cX = aX, cY = aY, cZ = aZ;
              const int kp = (k + 2 < nn) ? k + 2 : nn - 1;   // branchless clamp
              const uint jj = __float_as_uint(fb[kp][24]);
              const uint* xp = (const uint*)(xmpC + jj + tb);
              aX = xp[0]; aY = xp[1]; aZ = xp[2];
              edge_compute(k, cX, cY, cZ);
            }
            if (++k >= nn) break;
            {                                    // edge k (set B)
              const uint cX = bX, cY = bY, cZ = bZ;
              const int kp = (k + 2 < nn) ? k + 2 : nn - 1;
              const uint jj = __float_as_uint(fb[kp][24]);
              const uint* xp = (const uint*)(xmpC + jj + tb);
              bX = xp[0]; bY = xp[1]; bZ = xp[2];
              edge_compute(k, cX, cY, cZ);
            }
            ++k;
          }
        }

        // unconditional per-atom flush (handles deg==0 too)
        out[(size_t)a * FD + t] = q[(size_t)a * FD + t] + acq;
        const size_t mi = (size_t)a * F3;
        out[NQ + mi + t]       = mu[mi + t]       + ac0;
        out[NQ + mi + 128 + t] = mu[mi + 128 + t] + ac1;
        out[NQ + mi + 256 + t] = mu[mi + 256 + t] + ac2;
      }
    }
  }
}

extern "C" void kernel_launch(void* const* d_in, const int* in_sizes, int n_in,
                              void* d_out, int out_size, void* d_ws, size_t ws_size,
                              hipStream_t stream) {
  const float* q   = (const float*)d_in[0];
  const float* mu  = (const float*)d_in[1];
  const int*   eix = (const int*)d_in[2];
  const float* ew  = (const float*)d_in[3];
  const float* W1  = (const float*)d_in[4];
  const float* b1  = (const float*)d_in[5];
  const float* W2  = (const float*)d_in[6];
  const float* b2v = (const float*)d_in[7];
  const float* Wf  = (const float*)d_in[8];
  const float* bfv = (const float*)d_in[9];
  float* out = (float*)d_out;

  // Workspace: [xmp 12B*N*128 (30.7MB) | cnt 80KB | basisS 16B*N*cap (25.6MB @80)]
  char* w = (char*)d_ws;
  uint* xmp = (uint*)w;  w += (size_t)NATOMS * FD * 3 * sizeof(uint);
  int*  cnt = (int*)w;   w += (size_t)NATOMS * sizeof(int);
  uint4* basisS = (uint4*)w;

  const size_t used = (size_t)NATOMS * FD * 3 * sizeof(uint) + (size_t)NATOMS * sizeof(int);
  int cap = CAPMAX;
  if (ws_size > used) {
    const size_t mx = (ws_size - used) / ((size_t)NATOMS * 16);
    if ((size_t)cap > mx) cap = (int)mx;       // degrade gracefully if ws tight
  }

  hipMemsetAsync(cnt, 0, (size_t)NATOMS * sizeof(int), stream);

  // co-residency-safe grid: occupancy query (host-only, capture-safe)
  int maxB = 0;
  if (hipOccupancyMaxActiveBlocksPerMultiprocessor(&maxB, fused_kernel, BLK, 0)
          != hipSuccess || maxB < 1)
    maxB = 4;                                   // conservative fallback
  long grid = (long)maxB * 256;
  if (grid > GRID_TARGET) grid = GRID_TARGET;

  void* args[] = {
    (void*)&eix, (void*)&ew, (void*)&cnt, (void*)&basisS, (void*)&cap,
    (void*)&q, (void*)&mu, (void*)&W1, (void*)&b1, (void*)&W2, (void*)&b2v,
    (void*)&xmp, (void*)&Wf, (void*)&bfv, (void*)&out
  };
  hipLaunchCooperativeKernel(fused_kernel, dim3((uint)grid), dim3(BLK),
                             args, 0, stream);
}

// Round 8
// 391.654 us; speedup vs baseline: 1.8683x; 1.8683x over previous
//
#include <hip/hip_runtime.h>
#include <hip/hip_bf16.h>

typedef unsigned int uint;
typedef unsigned short ushort;
typedef float v2f __attribute__((ext_vector_type(2)));
typedef uint v4u __attribute__((ext_vector_type(4)));   // clang vec for nt-store

#define NATOMS 20000
#define NEDGES 640000
#define FD 128
#define F3 384
#define NR 20
#define MAPB 16     // atoms per block, MLP
#define GAPB 2      // atoms per block, gather
#define CAPMAX 80   // bin capacity: mean degree 32, ~11 sigma headroom
#define CNTS 16     // cnt stride in ints: one 64B line per atom (anti-bounce)

__device__ __forceinline__ uint f2bfu(float f) {   // f32 -> bf16 bits, RNE
  const uint u = __float_as_uint(f);
  return (u + 0x7FFFu + ((u >> 16) & 1u)) >> 16;
}
__device__ __forceinline__ float bflo(uint u) { return __uint_as_float(u << 16); }
__device__ __forceinline__ float bfhi(uint u) { return __uint_as_float(u & 0xFFFF0000u); }

// ---------------------------------------------------------------------------
// Phase 1 (runs FIRST): x = silu(q@W1+b1)@W2+b2; pack per (atom,feature t) a
// 12B record [x0|x1, x2|m0, m1|m2] (bf16) -> gather reads ONE dwordx3/edge.
// Also zeroes the padded cnt array (256 ints per block) -> memset dispatch
// and its boundary are eliminated; prep (next in stream) sees zeros.
// K-loops quad-unrolled with float4 LDS broadcasts.
// ---------------------------------------------------------------------------
__global__ __launch_bounds__(128) void mlp_kernel(
    const float* __restrict__ q, const float* __restrict__ mu,
    const float* __restrict__ W1, const float* __restrict__ b1,
    const float* __restrict__ W2, const float* __restrict__ b2v,
    uint* __restrict__ xmp, int* __restrict__ cnt)
{
  __shared__ float qL[MAPB][FD];
  __shared__ float hL[MAPB][FD];
  const int t = threadIdx.x;
  const int a0 = blockIdx.x * MAPB;

  // zero padded cnt: 1250 blocks x 256 ints = 320000 = NATOMS*CNTS
  cnt[blockIdx.x * 256 + t] = 0;
  cnt[blockIdx.x * 256 + 128 + t] = 0;

  #pragma unroll
  for (int a = 0; a < MAPB; ++a) qL[a][t] = q[(size_t)(a0 + a) * FD + t];
  __syncthreads();

  float hacc[MAPB];
  const float bb1 = b1[t];
  #pragma unroll
  for (int a = 0; a < MAPB; ++a) hacc[a] = bb1;
  for (int i = 0; i < FD; i += 4) {
    const float w0 = W1[(size_t)i * FD + t];
    const float w1 = W1[(size_t)(i + 1) * FD + t];
    const float w2 = W1[(size_t)(i + 2) * FD + t];
    const float w3 = W1[(size_t)(i + 3) * FD + t];
    #pragma unroll
    for (int a = 0; a < MAPB; ++a) {
      const float4 qv = *(const float4*)&qL[a][i];   // b128 broadcast
      hacc[a] += qv.x * w0 + qv.y * w1 + qv.z * w2 + qv.w * w3;
    }
  }
  #pragma unroll
  for (int a = 0; a < MAPB; ++a) hL[a][t] = hacc[a] / (1.f + __expf(-hacc[a]));
  __syncthreads();

  float x0[MAPB], x1[MAPB], x2[MAPB];
  const float c0 = b2v[t], c1 = b2v[FD + t], c2 = b2v[2 * FD + t];
  #pragma unroll
  for (int a = 0; a < MAPB; ++a) { x0[a] = c0; x1[a] = c1; x2[a] = c2; }
  for (int i = 0; i < FD; i += 4) {
    const float wa0 = W2[(size_t)i * F3 + t];
    const float wa1 = W2[(size_t)(i + 1) * F3 + t];
    const float wa2 = W2[(size_t)(i + 2) * F3 + t];
    const float wa3 = W2[(size_t)(i + 3) * F3 + t];
    const float wb0 = W2[(size_t)i * F3 + FD + t];
    const float wb1 = W2[(size_t)(i + 1) * F3 + FD + t];
    const float wb2 = W2[(size_t)(i + 2) * F3 + FD + t];
    const float wb3 = W2[(size_t)(i + 3) * F3 + FD + t];
    const float wc0 = W2[(size_t)i * F3 + 2 * FD + t];
    const float wc1 = W2[(size_t)(i + 1) * F3 + 2 * FD + t];
    const float wc2 = W2[(size_t)(i + 2) * F3 + 2 * FD + t];
    const float wc3 = W2[(size_t)(i + 3) * F3 + 2 * FD + t];
    #pragma unroll
    for (int a = 0; a < MAPB; ++a) {
      const float4 hv = *(const float4*)&hL[a][i];   // b128 broadcast
      x0[a] += hv.x * wa0 + hv.y * wa1 + hv.z * wa2 + hv.w * wa3;
      x1[a] += hv.x * wb0 + hv.y * wb1 + hv.z * wb2 + hv.w * wb3;
      x2[a] += hv.x * wc0 + hv.y * wc1 + hv.z * wc2 + hv.w * wc3;
    }
  }
  #pragma unroll
  for (int a = 0; a < MAPB; ++a) {
    const int n = a0 + a;
    const float* ma = mu + (size_t)n * F3;
    const float m0 = ma[t], m1 = ma[FD + t], m2 = ma[2 * FD + t];
    uint* dst = xmp + ((size_t)n * FD + t) * 3;
    dst[0] = f2bfu(x0[a]) | (f2bfu(x1[a]) << 16);
    dst[1] = f2bfu(x2[a]) | (f2bfu(m0) << 16);
    dst[2] = f2bfu(m1)    | (f2bfu(m2) << 16);
  }
}

// ---------------------------------------------------------------------------
// Prep: 16B record {ew0,ew1,ew2, j*1536} into atom i's fixed bin.
// cnt padded to one 64B line per atom: the 640K fetch-adds no longer share
// lines across atoms (suspected cross-XCD line bouncing = prep's ~120us).
// Nontemporal scatter store (via clang ext_vector) skips the write-allocate.
// ---------------------------------------------------------------------------
__global__ __launch_bounds__(256) void prep_kernel(
    const int* __restrict__ eidx, const float* __restrict__ ew,
    int* __restrict__ cnt, uint* __restrict__ basisS, int cap)
{
  const int e = blockIdx.x * 256 + threadIdx.x;
  if (e >= NEDGES) return;
  const int i = eidx[e];
  const int j = eidx[NEDGES + e];
  const int pos = atomicAdd(&cnt[(size_t)i * CNTS], 1);
  if (pos >= cap) return;                    // runtime guard (never at cap=80)

  v4u r;
  r.x = __float_as_uint(ew[(size_t)e * 3 + 0]);
  r.y = __float_as_uint(ew[(size_t)e * 3 + 1]);
  r.z = __float_as_uint(ew[(size_t)e * 3 + 2]);
  r.w = (uint)j * (uint)(FD * 3 * 4);        // byte offset into xmp (j*1536)
  v4u* dst = (v4u*)(basisS + ((size_t)i * cap + pos) * 4);
  __builtin_nontemporal_store(r, dst);
}

// ---------------------------------------------------------------------------
// Phase 2: UNCHANGED from the verified R5 kernel (194us standalone) except
// cnt read is cnt[a*CNTS]. 128-thread blocks, GAPB=2 atoms, fixed bins,
// thread t owns filter columns {t,128+t,256+t}, launch_bounds(128,3) keeps
// the 60-VGPR Wf slice resident, 2x unroll + branchless distance-2 prefetch.
// ---------------------------------------------------------------------------
__global__ __launch_bounds__(128, 3) void gather_kernel(
    const float* __restrict__ q, const float* __restrict__ mu,
    const uint* __restrict__ xmp,
    const float* __restrict__ Wf, const float* __restrict__ bfv,
    const int* __restrict__ cnt, const uint4* __restrict__ basisS,
    float* __restrict__ out, int cap)
{
  __shared__ float fb[64][28];     // [0..19] basis f32, [20..23] env+dir, [24] jbyte
  const int t = threadIdx.x;
  const int a0 = blockIdx.x * GAPB;
  const int tb = t * 12;
  const char* xmpC = (const char*)xmp;

  v2f wf0[10], wf1[10], wf2[10];
  #pragma unroll
  for (int r = 0; r < 10; ++r) {
    wf0[r] = (v2f){Wf[(size_t)(2 * r) * F3 + t],       Wf[(size_t)(2 * r + 1) * F3 + t]};
    wf1[r] = (v2f){Wf[(size_t)(2 * r) * F3 + 128 + t], Wf[(size_t)(2 * r + 1) * F3 + 128 + t]};
    wf2[r] = (v2f){Wf[(size_t)(2 * r) * F3 + 256 + t], Wf[(size_t)(2 * r + 1) * F3 + 256 + t]};
  }
  const float bias0 = bfv[t], bias1 = bfv[128 + t], bias2 = bfv[256 + t];

  float acq = 0.f, ac0 = 0.f, ac1 = 0.f, ac2 = 0.f;
  const size_t NQ = (size_t)NATOMS * FD;

  auto edge_compute = [&](int k, uint pX, uint pY, uint pZ) {
    const float* fk = fb[k];
    const float4 M = *(const float4*)(fk + 20);  // env, dir0..2 (b128 broadcast)
    v2f s0 = (v2f){0.f, 0.f}, s1 = (v2f){0.f, 0.f}, s2 = (v2f){0.f, 0.f};
    #pragma unroll
    for (int r4 = 0; r4 < 5; ++r4) {             // 5x ds_read_b128 broadcast
      const float4 bv = ((const float4*)fk)[r4];
      const v2f blo = (v2f){bv.x, bv.y};
      const v2f bhi = (v2f){bv.z, bv.w};
      s0 += blo * wf0[2 * r4]; s0 += bhi * wf0[2 * r4 + 1];
      s1 += blo * wf1[2 * r4]; s1 += bhi * wf1[2 * r4 + 1];
      s2 += blo * wf2[2 * r4]; s2 += bhi * wf2[2 * r4 + 1];
    }
    const float env = M.x;
    const float f0 = s0.x + s0.y + env * bias0;
    const float f1 = s1.x + s1.y + env * bias1;
    const float f2 = s2.x + s2.y + env * bias2;

    acq += f0 * bflo(pX);
    const float dmuR = f1 * bfhi(pX);
    const float dmm  = f2 * bflo(pY);
    ac0 += dmuR * M.y + dmm * bfhi(pY);
    ac1 += dmuR * M.z + dmm * bflo(pZ);
    ac2 += dmuR * M.w + dmm * bfhi(pZ);
  };

  for (int aa = 0; aa < GAPB; ++aa) {
    const int a = a0 + aa;
    int deg = cnt[(size_t)a * CNTS];
    if (deg > cap) deg = cap;                    // guard (never at cap=80)
    const uint4* bin = basisS + (size_t)a * cap;

    for (int cb = 0; cb < deg; cb += 64) {
      const int nn = min(64, deg - cb);
      __syncthreads();                           // fb reuse hazard
      if (t < nn) {
        const uint4 r = bin[cb + t];             // direct 16B coalesced load
        const float w0 = __uint_as_float(r.x);
        const float w1 = __uint_as_float(r.y);
        const float w2 = __uint_as_float(r.z);
        const float d = sqrtf(w0 * w0 + w1 * w1 + w2 * w2);
        const float invd = 1.f / d;
        float s1v, c1v;
        __sincosf(d * 0.628318530717958f, &s1v, &c1v);  // theta = pi*d/5
        const float env = (d < 5.f) ? 0.5f * (c1v + 1.f) : 0.f;
        fb[t][20] = env;
        fb[t][21] = w0 * invd;
        fb[t][22] = w1 * invd;
        fb[t][23] = w2 * invd;
        fb[t][24] = __uint_as_float(r.w);               // jbyte bits
        float vp = 0.f, vc = s1v * env * invd;
        const float tc2 = 2.f * c1v;
        #pragma unroll
        for (int r2 = 0; r2 < NR; ++r2) { fb[t][r2] = vc; const float vn = tc2 * vc - vp; vp = vc; vc = vn; }
      }
      __syncthreads();

      // prologue: fill both register sets (edges 0 and 1, clamped)
      uint aX, aY, aZ, bX, bY, bZ;
      {
        const uint j0 = __float_as_uint(fb[0][24]);
        const uint* xp = (const uint*)(xmpC + j0 + tb);
        aX = xp[0]; aY = xp[1]; aZ = xp[2];
        const int k1 = (nn > 1) ? 1 : 0;
        const uint j1 = __float_as_uint(fb[k1][24]);
        const uint* yp = (const uint*)(xmpC + j1 + tb);
        bX = yp[0]; bY = yp[1]; bZ = yp[2];
      }

      int k = 0;
      while (k < nn) {
        {                                        // edge k (set A)
          const uint cX = aX, cY = aY, cZ = aZ;
          const int kp = (k + 2 < nn) ? k + 2 : nn - 1;   // branchless clamp
          const uint jj = __float_as_uint(fb[kp][24]);
          const uint* xp = (const uint*)(xmpC + jj + tb);
          aX = xp[0]; aY = xp[1]; aZ = xp[2];
          edge_compute(k, cX, cY, cZ);
        }
        if (++k >= nn) break;
        {                                        // edge k (set B)
          const uint cX = bX, cY = bY, cZ = bZ;
          const int kp = (k + 2 < nn) ? k + 2 : nn - 1;
          const uint jj = __float_as_uint(fb[kp][24]);
          const uint* xp = (const uint*)(xmpC + jj + tb);
          bX = xp[0]; bY = xp[1]; bZ = xp[2];
          edge_compute(k, cX, cY, cZ);
        }
        ++k;
      }
    }

    // unconditional per-atom flush (handles deg==0 too)
    out[(size_t)a * FD + t] = q[(size_t)a * FD + t] + acq;
    const size_t mi = (size_t)a * F3;
    out[NQ + mi + t]       = mu[mi + t]       + ac0;
    out[NQ + mi + 128 + t] = mu[mi + 128 + t] + ac1;
    out[NQ + mi + 256 + t] = mu[mi + 256 + t] + ac2;
    acq = ac0 = ac1 = ac2 = 0.f;
  }
}

extern "C" void kernel_launch(void* const* d_in, const int* in_sizes, int n_in,
                              void* d_out, int out_size, void* d_ws, size_t ws_size,
                              hipStream_t stream) {
  const float* q   = (const float*)d_in[0];
  const float* mu  = (const float*)d_in[1];
  const int*   eix = (const int*)d_in[2];
  const float* ew  = (const float*)d_in[3];
  const float* W1  = (const float*)d_in[4];
  const float* b1  = (const float*)d_in[5];
  const float* W2  = (const float*)d_in[6];
  const float* b2v = (const float*)d_in[7];
  const float* Wf  = (const float*)d_in[8];
  const float* bfv = (const float*)d_in[9];
  float* out = (float*)d_out;

  // Workspace: [xmp 30.7MB | cnt(padded) 1.28MB | basisS 16B*N*cap (25.6MB @80)]
  char* w = (char*)d_ws;
  uint* xmp = (uint*)w;  w += (size_t)NATOMS * FD * 3 * sizeof(uint);
  int*  cnt = (int*)w;   w += (size_t)NATOMS * CNTS * sizeof(int);
  uint* basisS = (uint*)w;

  const size_t used = (size_t)NATOMS * FD * 3 * sizeof(uint)
                    + (size_t)NATOMS * CNTS * sizeof(int);
  int cap = CAPMAX;
  if (ws_size > used) {
    const size_t mx = (ws_size - used) / ((size_t)NATOMS * 16);
    if ((size_t)cap > mx) cap = (int)mx;       // degrade gracefully if ws tight
  }

  // mlp first (also zeroes cnt) -> prep -> gather. 3 dispatches, no memset.
  mlp_kernel<<<NATOMS / MAPB, 128, 0, stream>>>(q, mu, W1, b1, W2, b2v,
                                                xmp, cnt);

  prep_kernel<<<(NEDGES + 255) / 256, 256, 0, stream>>>(eix, ew, cnt,
                                                        basisS, cap);

  gather_kernel<<<NATOMS / GAPB, 128, 0, stream>>>(q, mu, xmp, Wf, bfv,
                                                   cnt, (const uint4*)basisS,
                                                   out, cap);
}